// Round 20
// baseline (96.447 us; speedup 1.0000x reference)
//
#include <hip/hip_runtime.h>
#include <hip/hip_bf16.h>

typedef __attribute__((ext_vector_type(8))) short short8;
typedef __attribute__((ext_vector_type(4))) short short4v;
typedef __attribute__((ext_vector_type(4))) float f32x4;
typedef __attribute__((ext_vector_type(16))) float f32x16;
typedef __attribute__((ext_vector_type(4))) int i32x4;
typedef __attribute__((ext_vector_type(16))) int i32x16;
typedef __attribute__((ext_vector_type(2))) unsigned u32x2;

namespace {
constexpr int NSEQ = 2048;
constexpr int NHEAD = 16;
constexpr int NDIM = 128;
constexpr int BKV = 32;
constexpr int ROWI = NHEAD * NDIM;   // 2048 ints per seq row
constexpr int MID = 34;              // 2-way balanced split point
constexpr int NROWSH = 2 * 1024 * NHEAD;            // heavy rows (q>=1024) = 32768
constexpr size_t NPARTH = (size_t)NROWSH * NDIM;    // elems per heavy partial
}

__device__ __forceinline__ short f2bf(float f) {             // RNE
    union { float f; unsigned u; } x; x.f = f;
    unsigned u = (x.u + 0x7fffu + ((x.u >> 16) & 1u)) >> 16;
    return (short)u;
}
__device__ __forceinline__ float bf2f(short s) {
    union { unsigned u; float f; } x; x.u = ((unsigned)(unsigned short)s) << 16;
    return x.f;
}
__device__ __forceinline__ unsigned pack8(const int4 &a) {
    return (unsigned)(a.x & 255) | ((unsigned)(a.y & 255) << 8) |
           ((unsigned)(a.z & 255) << 16) | ((unsigned)a.w << 24);
}
// pack two ints (|v|<=255 -> exact) into one dword of 2 bf16: [bf16(a) | bf16(b)<<16]
__device__ __forceinline__ unsigned cvtpk2i(int a, int b) {
    float fa = (float)a, fb = (float)b;
    unsigned d;
    asm("v_cvt_pk_bf16_f32 %0, %1, %2" : "=v"(d) : "v"(fa), "v"(fb));
    return d;
}
__device__ __forceinline__ void plswap(unsigned &a, unsigned &b) {
#if __has_builtin(__builtin_amdgcn_permlane32_swap)
    u32x2 r = __builtin_amdgcn_permlane32_swap(a, b, false, false);
    a = r[0]; b = r[1];
#else
    asm volatile("v_permlane32_swap_b32 %0, %1" : "+v"(a), "+v"(b));
#endif
}

// MODE: 0 = exact 512-block; 1 = 2-way heavy split (round-10/12 structure)
// NOTE: launch_bounds arg2 MUST stay <=2: higher caps VGPR at 64 -> catastrophic scratch
// spill (rounds 9/11/13: VGPR_Count 64, WRITE_SIZE 152-466 MB).
template<int MODE>
__global__ __launch_bounds__(256, 2)
void qattn_fwd(const int* __restrict__ qq, const int* __restrict__ kq,
               const int* __restrict__ vq, const float* __restrict__ qsc,
               const float* __restrict__ ksc, const float* __restrict__ vsc,
               float* __restrict__ out, unsigned short* __restrict__ po,
               float* __restrict__ ml)
{
    const int id = blockIdx.x;
    const int bh = id & 31;                        // same bh -> same XCD (32%8==0)
    const int b = bh >> 4, h = bh & 15;
    const int t = threadIdx.x;
    const int lane = t & 63;
    const int l31 = lane & 31;
    const int h5 = lane >> 5;
    const int w = t >> 6;                          // wave 0..3

    __shared__ __align__(16) unsigned k_lds[2][BKV * 32];  // 8 KB total, packed i8 rows, XOR-swz

    const float sc2 = qsc[h] * ksc[h] * (0.08838834764831845f * 1.4426950408889634f); // /sqrt(D)*log2e
    const float vscale = vsc[h];

    const int* kB = kq + (size_t)b * NSEQ * ROWI + h * NDIM;
    const int* vB = vq + (size_t)b * NSEQ * ROWI + h * NDIM;

    // K staging decomposition (256 threads)
    const int kr  = t >> 3;            // K: row 0..31
    const int db  = t & 7;             // K: 16-int group (-> 4 packed dwords)

    // outMode: 0 = exact -> out; 1 = heavy-layout partial (part 0/1)
    auto run_segment = [&](int q0, int tBeg, int tEnd, int outMode, int part) {
        __syncthreads();               // protect LDS reuse across segments
        // ---- Q fragments (B-operand of 32x32x32_i8): lane owns q col = q0+l31 ----
        i32x4 qf[4];
        {
            const int* qp = qq + (size_t)(b * NSEQ + q0 + l31) * ROWI + h * NDIM + h5 * 16;
            #pragma unroll
            for (int c = 0; c < 4; ++c) {
                int4 a0 = *(const int4*)(qp + c * 32);
                int4 a1 = *(const int4*)(qp + c * 32 + 4);
                int4 a2 = *(const int4*)(qp + c * 32 + 8);
                int4 a3 = *(const int4*)(qp + c * 32 + 12);
                i32x4 f = { (int)pack8(a0), (int)pack8(a1), (int)pack8(a2), (int)pack8(a3) };
                qf[c] = f;
            }
        }
        f32x16 o_acc[4];
        #pragma unroll
        for (int dt = 0; dt < 4; ++dt)
            #pragma unroll
            for (int r = 0; r < 16; ++r) o_acc[dt][r] = 0.f;
        float m_run = -1e30f, l_run = 0.f;
        const int q_hi = q0 + 31;

        int4 ka0, ka1, ka2, ka3;
        auto ISSUE = [&](int tt) {
            const int kv = tt * BKV;
            const int* kp = kB + (kv + kr) * ROWI + db * 16;
            ka0 = *(const int4*)kp;       ka1 = *(const int4*)(kp + 4);
            ka2 = *(const int4*)(kp + 8); ka3 = *(const int4*)(kp + 12);
        };
        auto WRITE = [&](int buf) {
            i32x4 kk = { (int)pack8(ka0), (int)pack8(ka1), (int)pack8(ka2), (int)pack8(ka3) };
            *(i32x4*)&k_lds[buf][kr * 32 + ((db * 4) ^ ((kr & 7) << 2))] = kk;   // 16B-group XOR swz
        };

        ISSUE(tBeg);
        for (int tt = tBeg; tt < tEnd; ++tt) {
            const int buf = (tt - tBeg) & 1;
            WRITE(buf);
            if (tt + 1 < tEnd) ISSUE(tt + 1);
            __syncthreads();

            const int kv0 = tt * BKV;
            if (kv0 > q_hi) continue;      // wave-uniform causal skip

            // ---- V direct loads (coalesced over l31; L2/L3-resident; consumed after softmax) ----
            int vv[4][16];
            #pragma unroll
            for (int dt = 0; dt < 4; ++dt) {
                const int* vp = vB + (size_t)(kv0 + h5 * 8) * ROWI + dt * 32 + l31;
                #pragma unroll
                for (int hf = 0; hf < 2; ++hf)
                    #pragma unroll
                    for (int e = 0; e < 8; ++e)
                        vv[dt][hf * 8 + e] = vp[(hf * 16 + e) * ROWI];
            }

            // ---- QK^T (swapped, int8 exact): C = S^T, col = l31 = q, kv = (r&3)+8*(r>>2)+4*h5 ----
            i32x16 s;
            #pragma unroll
            for (int r = 0; r < 16; ++r) s[r] = 0;
            __builtin_amdgcn_s_setprio(1);
            #pragma unroll
            for (int c = 0; c < 4; ++c) {
                const i32x4 kb = *(const i32x4*)&k_lds[buf][l31 * 32 + ((c * 8 + h5 * 4) ^ ((l31 & 7) << 2))];
                s = __builtin_amdgcn_mfma_i32_32x32x32_i8(kb, qf[c], s, 0, 0, 0);
            }
            __builtin_amdgcn_s_setprio(0);

            // ---- mask (diag tile only) + int->f32 (exact, |s| < 2^24) ----
            float sv[16];
            if (kv0 < q0) {
                #pragma unroll
                for (int r = 0; r < 16; ++r) sv[r] = (float)s[r];
            } else {                       // kv0 == q0 diag
                #pragma unroll
                for (int r = 0; r < 16; ++r) {
                    const int kvr = (r & 3) + 8 * (r >> 2) + 4 * h5;
                    sv[r] = (kvr <= l31) ? (float)s[r] : -1e30f;
                }
            }

            // ---- in-register softmax (raw-s domain; sc2 > 0 so max commutes) ----
            float rmax = sv[0];
            #pragma unroll
            for (int r = 1; r < 16; ++r) rmax = fmaxf(rmax, sv[r]);
            rmax = fmaxf(rmax, __shfl_xor(rmax, 32, 64));      // cross-half max
            const bool needr = (rmax - m_run) * sc2 > 8.0f;    // T13 defer-rescale
            if (__any((int)needr)) {
                const float mn = fmaxf(m_run, rmax);
                const float sf = exp2f((m_run - mn) * sc2);
                m_run = mn;
                l_run *= sf;
                #pragma unroll
                for (int dt = 0; dt < 4; ++dt)
                    #pragma unroll
                    for (int r = 0; r < 16; ++r) o_acc[dt][r] *= sf;
            }
            const float nm = m_run * sc2;
            float p[16];
            float ps = 0.f;
            #pragma unroll
            for (int r = 0; r < 16; ++r) {
                p[r] = exp2f(__builtin_fmaf(sv[r], sc2, -nm));
                ps += p[r];
            }
            ps += __shfl_xor(ps, 32, 64);                      // cross-half sum
            l_run += ps;

            // ---- P -> bf16 B-frags fully in-register (T12) ----
            unsigned pw0[4], pw1[4];
            {
                unsigned A0, A1, B0, B1;
                asm("v_cvt_pk_bf16_f32 %0, %1, %2" : "=v"(A0) : "v"(p[0]),  "v"(p[1]));
                asm("v_cvt_pk_bf16_f32 %0, %1, %2" : "=v"(A1) : "v"(p[2]),  "v"(p[3]));
                asm("v_cvt_pk_bf16_f32 %0, %1, %2" : "=v"(B0) : "v"(p[4]),  "v"(p[5]));
                asm("v_cvt_pk_bf16_f32 %0, %1, %2" : "=v"(B1) : "v"(p[6]),  "v"(p[7]));
                plswap(A0, B0);
                plswap(A1, B1);
                pw0[0] = A0; pw0[1] = A1; pw0[2] = B0; pw0[3] = B1;
                asm("v_cvt_pk_bf16_f32 %0, %1, %2" : "=v"(A0) : "v"(p[8]),  "v"(p[9]));
                asm("v_cvt_pk_bf16_f32 %0, %1, %2" : "=v"(A1) : "v"(p[10]), "v"(p[11]));
                asm("v_cvt_pk_bf16_f32 %0, %1, %2" : "=v"(B0) : "v"(p[12]), "v"(p[13]));
                asm("v_cvt_pk_bf16_f32 %0, %1, %2" : "=v"(B1) : "v"(p[14]), "v"(p[15]));
                plswap(A0, B0);
                plswap(A1, B1);
                pw1[0] = A0; pw1[1] = A1; pw1[2] = B0; pw1[3] = B1;
            }
            union { unsigned u4[4]; short8 v; } pf0, pf1;
            pf0.u4[0]=pw0[0]; pf0.u4[1]=pw0[1]; pf0.u4[2]=pw0[2]; pf0.u4[3]=pw0[3];
            pf1.u4[0]=pw1[0]; pf1.u4[1]=pw1[1]; pf1.u4[2]=pw1[2]; pf1.u4[3]=pw1[3];

            // ---- PV (swapped): O^T[d][q] += V^T[d][kv] * P^T[kv][q]; V frags from registers ----
            __builtin_amdgcn_s_setprio(1);
            #pragma unroll
            for (int dt = 0; dt < 4; ++dt) {
                union { unsigned u4[4]; short8 v; } fa, fb;
                #pragma unroll
                for (int j = 0; j < 4; ++j) {
                    fa.u4[j] = cvtpk2i(vv[dt][2 * j],     vv[dt][2 * j + 1]);
                    fb.u4[j] = cvtpk2i(vv[dt][8 + 2 * j], vv[dt][8 + 2 * j + 1]);
                }
                o_acc[dt] = __builtin_amdgcn_mfma_f32_32x32x16_bf16(fa.v, pf0.v, o_acc[dt], 0, 0, 0);
                o_acc[dt] = __builtin_amdgcn_mfma_f32_32x32x16_bf16(fb.v, pf1.v, o_acc[dt], 0, 0, 0);
            }
            __builtin_amdgcn_s_setprio(0);
        }

        // ---- epilogue ----
        const int qrow = q0 + l31;
        if (outMode == 0) {
            const float sr = vscale / l_run;
            float* op = out + ((size_t)(b * NSEQ + qrow) * NHEAD + h) * NDIM;
            #pragma unroll
            for (int dt = 0; dt < 4; ++dt) {
                #pragma unroll
                for (int gq = 0; gq < 4; ++gq) {
                    f32x4 v = { o_acc[dt][gq * 4 + 0] * sr, o_acc[dt][gq * 4 + 1] * sr,
                                o_acc[dt][gq * 4 + 2] * sr, o_acc[dt][gq * 4 + 3] * sr };
                    *(f32x4*)(op + dt * 32 + 8 * gq + 4 * h5) = v;
                }
            }
        } else {
            const size_t hr = ((size_t)b * 1024 + (qrow - 1024)) * NHEAD + h;
            short* pp = (short*)(po + (size_t)part * NPARTH + hr * NDIM);
            #pragma unroll
            for (int dt = 0; dt < 4; ++dt) {
                #pragma unroll
                for (int gq = 0; gq < 4; ++gq) {
                    short4v v = { f2bf(o_acc[dt][gq * 4 + 0]), f2bf(o_acc[dt][gq * 4 + 1]),
                                  f2bf(o_acc[dt][gq * 4 + 2]), f2bf(o_acc[dt][gq * 4 + 3]) };
                    *(short4v*)(pp + dt * 32 + 8 * gq + 4 * h5) = v;
                }
            }
            if (h5 == 0) {
                float* mlp = ml + (size_t)part * (2 * NROWSH) + hr * 2;
                mlp[0] = m_run;
                mlp[1] = l_run;
            }
        }
    };

    if constexpr (MODE == 1) {
        const int u = id >> 5;                 // 0..15
        const int k = u & 7;                   // pair index
        const int role = u >> 3;               // 0 = A, 1 = B
        const int jqH = 15 - k, jqL = k;
        const int TH = (16 - k) * 4, TL = (k + 1) * 4;
        const int q0H = jqH * 128 + w * 32;
        if (role == 0) {
            run_segment(q0H, 0, MID, 1, 0);                          // heavy prefix (34)
        } else {
            run_segment(q0H, MID, TH, 1, 1);                         // heavy suffix
            run_segment(jqL * 128 + w * 32, 0, TL, 0, 0);            // light exact; total 34
        }
    } else {
        const int idx = id >> 5;
        const int jq = (idx < 8) ? (15 - idx) : (idx - 8);
        run_segment(jq * 128 + w * 32, 0, (jq + 1) * 4, 0, 0);       // exact path
    }
}

// merge heavy-row 2-way partials
__global__ __launch_bounds__(256)
void qattn_combine2(const unsigned short* __restrict__ po, const float* __restrict__ ml,
                    const float* __restrict__ qsc, const float* __restrict__ ksc,
                    const float* __restrict__ vsc, float* __restrict__ out)
{
    const int gid = blockIdx.x * 256 + threadIdx.x;   // NROWSH*16 threads
    const int hr = gid >> 4;
    const int d0 = (gid & 15) * 8;
    const int h = hr & 15;
    const int q = 1024 + ((hr >> 4) & 1023);
    const int b = hr >> 14;
    const float sc2 = qsc[h] * ksc[h] * (0.08838834764831845f * 1.4426950408889634f);
    const float m0 = ml[(size_t)hr * 2 + 0], l0 = ml[(size_t)hr * 2 + 1];
    const float m1 = ml[(size_t)2 * NROWSH + hr * 2 + 0], l1 = ml[(size_t)2 * NROWSH + hr * 2 + 1];
    const float M = fmaxf(m0, m1);
    const float w0 = exp2f((m0 - M) * sc2);
    const float w1 = exp2f((m1 - M) * sc2);
    const float sr = vsc[h] / __builtin_fmaf(w0, l0, w1 * l1);
    const float a0 = w0 * sr, a1 = w1 * sr;
    const short* x = (const short*)po + (size_t)hr * NDIM + d0;
    const short* y = (const short*)(po + NPARTH) + (size_t)hr * NDIM + d0;
    short4v x0 = *(const short4v*)x;
    short4v x1 = *(const short4v*)(x + 4);
    short4v y0 = *(const short4v*)y;
    short4v y1 = *(const short4v*)(y + 4);
    f32x4 o0, o1;
    #pragma unroll
    for (int i = 0; i < 4; ++i) {
        o0[i] = __builtin_fmaf(a0, bf2f(x0[i]), a1 * bf2f(y0[i]));
        o1[i] = __builtin_fmaf(a0, bf2f(x1[i]), a1 * bf2f(y1[i]));
    }
    float* op = out + ((size_t)(b * NSEQ + q) * NHEAD + h) * NDIM + d0;
    *(f32x4*)op = o0;
    *(f32x4*)(op + 4) = o1;
}

extern "C" void kernel_launch(void* const* d_in, const int* in_sizes, int n_in,
                              void* d_out, int out_size, void* d_ws, size_t ws_size,
                              hipStream_t stream) {
    const int* qq = (const int*)d_in[0];
    const int* kq = (const int*)d_in[1];
    const int* vq = (const int*)d_in[2];
    const float* qsc = (const float*)d_in[3];
    const float* ksc = (const float*)d_in[4];
    const float* vsc = (const float*)d_in[5];
    float* out = (float*)d_out;
    (void)in_sizes; (void)n_in; (void)out_size;

    const size_t need2 = NPARTH * 2 * sizeof(unsigned short)      // two bf16 partial halves
                       + (size_t)NROWSH * 4 * sizeof(float);      // two (m,l) arrays
    if (ws_size >= need2) {
        unsigned short* po = (unsigned short*)d_ws;
        float* ml = (float*)((char*)d_ws + NPARTH * 2 * sizeof(unsigned short));
        qattn_fwd<1><<<dim3(512), dim3(256), 0, stream>>>(qq, kq, vq, qsc, ksc, vsc, out, po, ml);
        qattn_combine2<<<dim3(NROWSH * 16 / 256), dim3(256), 0, stream>>>(po, ml, qsc, ksc, vsc, out);
    } else {
        qattn_fwd<0><<<dim3(512), dim3(256), 0, stream>>>(qq, kq, vq, qsc, ksc, vsc, out, nullptr, nullptr);
    }
}

// Round 21
// 78.689 us; speedup vs baseline: 1.2257x; 1.2257x over previous
//
#include <hip/hip_runtime.h>
#include <hip/hip_bf16.h>

typedef __attribute__((ext_vector_type(8))) short short8;
typedef __attribute__((ext_vector_type(4))) short short4v;
typedef __attribute__((ext_vector_type(4))) float f32x4;
typedef __attribute__((ext_vector_type(16))) float f32x16;
typedef __attribute__((ext_vector_type(4))) int i32x4;
typedef __attribute__((ext_vector_type(16))) int i32x16;
typedef __attribute__((ext_vector_type(2))) unsigned u32x2;

namespace {
constexpr int NSEQ = 2048;
constexpr int NHEAD = 16;
constexpr int NDIM = 128;
constexpr int BKV = 32;
constexpr int VTS = 40;              // vt row stride (shorts); odd*16B -> conflict-free b128 column reads
constexpr int ROWI = NHEAD * NDIM;   // 2048 ints per seq row
constexpr int MID = 34;              // 2-way balanced split point
constexpr int NROWSH = 2 * 1024 * NHEAD;            // heavy rows (q>=1024) = 32768
constexpr size_t NPARTH = (size_t)NROWSH * NDIM;    // elems per heavy partial
}

// int in [-128,127] -> bf16 bits, exact
__device__ __forceinline__ short i2bf(int v) {
    union { float f; unsigned u; } x; x.f = (float)v;
    return (short)(x.u >> 16);
}
// float -> bf16 bits, RNE
__device__ __forceinline__ short f2bf(float f) {
    union { float f; unsigned u; } x; x.f = f;
    unsigned u = (x.u + 0x7fffu + ((x.u >> 16) & 1u)) >> 16;
    return (short)u;
}
__device__ __forceinline__ float bf2f(short s) {
    union { unsigned u; float f; } x; x.u = ((unsigned)(unsigned short)s) << 16;
    return x.f;
}
// 4 int32 (int8 values) -> 1 dword of 4 packed i8
__device__ __forceinline__ unsigned pack8(const int4 &a) {
    return (unsigned)(a.x & 255) | ((unsigned)(a.y & 255) << 8) |
           ((unsigned)(a.z & 255) << 16) | ((unsigned)a.w << 24);
}
// permlane32_swap: a' = [a_lo32 | b_lo32], b' = [a_hi32 | b_hi32]
__device__ __forceinline__ void plswap(unsigned &a, unsigned &b) {
#if __has_builtin(__builtin_amdgcn_permlane32_swap)
    u32x2 r = __builtin_amdgcn_permlane32_swap(a, b, false, false);
    a = r[0]; b = r[1];
#else
    asm volatile("v_permlane32_swap_b32 %0, %1" : "+v"(a), "+v"(b));  // a,b always distinct values here
#endif
}

// MODE: 0 = exact 512-block; 1 = 2-way heavy split (round-10 structure)
// NOTE: launch_bounds arg2 MUST stay <=2: arg2=4 empirically caps VGPR at 64 -> catastrophic
// scratch spill (rounds 9/11/13: VGPR_Count 64, WRITE_SIZE 152-466 MB).
template<int MODE>
__global__ __launch_bounds__(256, 2)
void qattn_fwd(const int* __restrict__ qq, const int* __restrict__ kq,
               const int* __restrict__ vq, const float* __restrict__ qsc,
               const float* __restrict__ ksc, const float* __restrict__ vsc,
               float* __restrict__ out, unsigned short* __restrict__ po,
               float* __restrict__ ml)
{
    const int id = blockIdx.x;
    const int bh = id & 31;                        // same bh -> same XCD (32%8==0)
    const int b = bh >> 4, h = bh & 15;
    const int t = threadIdx.x;
    const int lane = t & 63;
    const int l31 = lane & 31;
    const int h5 = lane >> 5;
    const int w = t >> 6;                          // wave 0..3

    __shared__ __align__(16) unsigned k_lds[2][BKV * 32];  // 8 KB, packed i8 rows, XOR-swz
    __shared__ __align__(16) short vt_lds[2][NDIM * VTS];  // 20 KB, V^T [d][kv]

    const float sc2 = qsc[h] * ksc[h] * (0.08838834764831845f * 1.4426950408889634f); // /sqrt(D)*log2e
    const float vscale = vsc[h];

    const int* kB = kq + (size_t)b * NSEQ * ROWI + h * NDIM;
    const int* vB = vq + (size_t)b * NSEQ * ROWI + h * NDIM;

    // staging decomposition (256 threads)
    const int kr  = t >> 3;            // K: row 0..31
    const int db  = t & 7;             // K: 16-int group (-> 4 packed dwords)
    const int kvh = t & 7;             // V: kv rows kvh*4..+3
    const int dgv = t >> 3;            // V: d cols dgv*4..+3

    // outMode: 0 = exact -> out; 1 = heavy-layout partial (part 0/1)
    auto run_segment = [&](int q0, int tBeg, int tEnd, int outMode, int part) {
        __syncthreads();               // protect LDS reuse across segments
        // ---- Q fragments (B-operand of 32x32x32_i8): lane owns q col = q0+l31,
        //      chunk c covers d = c*32 + h5*16 + [0,16), packed 4 dwords ----
        i32x4 qf[4];
        {
            const int* qp = qq + (size_t)(b * NSEQ + q0 + l31) * ROWI + h * NDIM + h5 * 16;
            #pragma unroll
            for (int c = 0; c < 4; ++c) {
                int4 a0 = *(const int4*)(qp + c * 32);
                int4 a1 = *(const int4*)(qp + c * 32 + 4);
                int4 a2 = *(const int4*)(qp + c * 32 + 8);
                int4 a3 = *(const int4*)(qp + c * 32 + 12);
                i32x4 f = { (int)pack8(a0), (int)pack8(a1), (int)pack8(a2), (int)pack8(a3) };
                qf[c] = f;
            }
        }
        f32x16 o_acc[4];
        #pragma unroll
        for (int dt = 0; dt < 4; ++dt)
            #pragma unroll
            for (int r = 0; r < 16; ++r) o_acc[dt][r] = 0.f;
        float m_run = -1e30f, l_run = 0.f;
        const int q_hi = q0 + 31;

        int4 ka0, ka1, ka2, ka3, va0, va1, va2, va3;
        auto ISSUE = [&](int tt) {
            const int kv = tt * BKV;
            const int* kp = kB + (kv + kr) * ROWI + db * 16;
            ka0 = *(const int4*)kp;       ka1 = *(const int4*)(kp + 4);
            ka2 = *(const int4*)(kp + 8); ka3 = *(const int4*)(kp + 12);
            const int* vp = vB + (kv + kvh * 4) * ROWI + dgv * 4;
            va0 = *(const int4*)vp;
            va1 = *(const int4*)(vp + ROWI);
            va2 = *(const int4*)(vp + 2 * ROWI);
            va3 = *(const int4*)(vp + 3 * ROWI);
        };
        auto WRITE = [&](int buf) {
            i32x4 kk = { (int)pack8(ka0), (int)pack8(ka1), (int)pack8(ka2), (int)pack8(ka3) };
            *(i32x4*)&k_lds[buf][kr * 32 + ((db * 4) ^ ((kr & 7) << 2))] = kk;   // 16B-group XOR swz
            short4v c0 = { i2bf(va0.x), i2bf(va1.x), i2bf(va2.x), i2bf(va3.x) };
            short4v c1 = { i2bf(va0.y), i2bf(va1.y), i2bf(va2.y), i2bf(va3.y) };
            short4v c2 = { i2bf(va0.z), i2bf(va1.z), i2bf(va2.z), i2bf(va3.z) };
            short4v c3 = { i2bf(va0.w), i2bf(va1.w), i2bf(va2.w), i2bf(va3.w) };
            short* vb = &vt_lds[buf][(dgv * 4) * VTS + kvh * 4];
            *(short4v*)(vb + 0 * VTS) = c0;
            *(short4v*)(vb + 1 * VTS) = c1;
            *(short4v*)(vb + 2 * VTS) = c2;
            *(short4v*)(vb + 3 * VTS) = c3;
        };

        ISSUE(tBeg);
        for (int tt = tBeg; tt < tEnd; ++tt) {
            const int buf = (tt - tBeg) & 1;
            WRITE(buf);
            if (tt + 1 < tEnd) ISSUE(tt + 1);
            __syncthreads();

            const int kv0 = tt * BKV;
            if (kv0 > q_hi) continue;      // wave-uniform causal skip

            // ---- QK^T (swapped, int8 exact): C = S^T, col = l31 = q, kv = (r&3)+8*(r>>2)+4*h5 ----
            i32x16 s;
            #pragma unroll
            for (int r = 0; r < 16; ++r) s[r] = 0;
            __builtin_amdgcn_s_setprio(1);
            #pragma unroll
            for (int c = 0; c < 4; ++c) {
                const i32x4 kb = *(const i32x4*)&k_lds[buf][l31 * 32 + ((c * 8 + h5 * 4) ^ ((l31 & 7) << 2))];
                s = __builtin_amdgcn_mfma_i32_32x32x32_i8(kb, qf[c], s, 0, 0, 0);
            }
            __builtin_amdgcn_s_setprio(0);

            // ---- mask (diag tile only) + int->f32 (exact, |s| < 2^24) ----
            float sv[16];
            if (kv0 < q0) {
                #pragma unroll
                for (int r = 0; r < 16; ++r) sv[r] = (float)s[r];
            } else {                       // kv0 == q0 diag
                #pragma unroll
                for (int r = 0; r < 16; ++r) {
                    const int kvr = (r & 3) + 8 * (r >> 2) + 4 * h5;
                    sv[r] = (kvr <= l31) ? (float)s[r] : -1e30f;
                }
            }

            // ---- in-register softmax (raw-s domain; sc2 > 0 so max commutes) ----
            float rmax = sv[0];
            #pragma unroll
            for (int r = 1; r < 16; ++r) rmax = fmaxf(rmax, sv[r]);
            rmax = fmaxf(rmax, __shfl_xor(rmax, 32, 64));      // cross-half max
            const bool needr = (rmax - m_run) * sc2 > 8.0f;    // T13 defer-rescale
            if (__any((int)needr)) {
                const float mn = fmaxf(m_run, rmax);
                const float sf = exp2f((m_run - mn) * sc2);
                m_run = mn;
                l_run *= sf;
                #pragma unroll
                for (int dt = 0; dt < 4; ++dt)
                    #pragma unroll
                    for (int r = 0; r < 16; ++r) o_acc[dt][r] *= sf;
            }
            const float nm = m_run * sc2;
            float p[16];
            float ps = 0.f;
            #pragma unroll
            for (int r = 0; r < 16; ++r) {
                p[r] = exp2f(__builtin_fmaf(sv[r], sc2, -nm));
                ps += p[r];
            }
            ps += __shfl_xor(ps, 32, 64);                      // cross-half sum
            l_run += ps;

            // ---- P -> bf16 B-frags fully in-register (T12) ----
            unsigned pw0[4], pw1[4];
            {
                unsigned A0, A1, B0, B1;
                asm("v_cvt_pk_bf16_f32 %0, %1, %2" : "=v"(A0) : "v"(p[0]),  "v"(p[1]));
                asm("v_cvt_pk_bf16_f32 %0, %1, %2" : "=v"(A1) : "v"(p[2]),  "v"(p[3]));
                asm("v_cvt_pk_bf16_f32 %0, %1, %2" : "=v"(B0) : "v"(p[4]),  "v"(p[5]));
                asm("v_cvt_pk_bf16_f32 %0, %1, %2" : "=v"(B1) : "v"(p[6]),  "v"(p[7]));
                plswap(A0, B0);
                plswap(A1, B1);
                pw0[0] = A0; pw0[1] = A1; pw0[2] = B0; pw0[3] = B1;
                asm("v_cvt_pk_bf16_f32 %0, %1, %2" : "=v"(A0) : "v"(p[8]),  "v"(p[9]));
                asm("v_cvt_pk_bf16_f32 %0, %1, %2" : "=v"(A1) : "v"(p[10]), "v"(p[11]));
                asm("v_cvt_pk_bf16_f32 %0, %1, %2" : "=v"(B0) : "v"(p[12]), "v"(p[13]));
                asm("v_cvt_pk_bf16_f32 %0, %1, %2" : "=v"(B1) : "v"(p[14]), "v"(p[15]));
                plswap(A0, B0);
                plswap(A1, B1);
                pw1[0] = A0; pw1[1] = A1; pw1[2] = B0; pw1[3] = B1;
            }
            union { unsigned u4[4]; short8 v; } pf0, pf1;
            pf0.u4[0]=pw0[0]; pf0.u4[1]=pw0[1]; pf0.u4[2]=pw0[2]; pf0.u4[3]=pw0[3];
            pf1.u4[0]=pw1[0]; pf1.u4[1]=pw1[1]; pf1.u4[2]=pw1[2]; pf1.u4[3]=pw1[3];

            // ---- PV (swapped): O^T[d][q] += V^T[d][kv] * P^T[kv][q] ----
            __builtin_amdgcn_s_setprio(1);
            #pragma unroll
            for (int dt = 0; dt < 4; ++dt) {
                const int drow = dt * 32 + l31;
                const short8 vb0 = *(const short8*)&vt_lds[buf][drow * VTS + h5 * 8];
                o_acc[dt] = __builtin_amdgcn_mfma_f32_32x32x16_bf16(vb0, pf0.v, o_acc[dt], 0, 0, 0);
                const short8 vb1 = *(const short8*)&vt_lds[buf][drow * VTS + 16 + h5 * 8];
                o_acc[dt] = __builtin_amdgcn_mfma_f32_32x32x16_bf16(vb1, pf1.v, o_acc[dt], 0, 0, 0);
            }
            __builtin_amdgcn_s_setprio(0);
        }

        // ---- epilogue ----
        const int qrow = q0 + l31;
        if (outMode == 0) {
            const float sr = vscale / l_run;
            float* op = out + ((size_t)(b * NSEQ + qrow) * NHEAD + h) * NDIM;
            #pragma unroll
            for (int dt = 0; dt < 4; ++dt) {
                #pragma unroll
                for (int gq = 0; gq < 4; ++gq) {
                    f32x4 v = { o_acc[dt][gq * 4 + 0] * sr, o_acc[dt][gq * 4 + 1] * sr,
                                o_acc[dt][gq * 4 + 2] * sr, o_acc[dt][gq * 4 + 3] * sr };
                    *(f32x4*)(op + dt * 32 + 8 * gq + 4 * h5) = v;
                }
            }
        } else {
            const size_t hr = ((size_t)b * 1024 + (qrow - 1024)) * NHEAD + h;
            short* pp = (short*)(po + (size_t)part * NPARTH + hr * NDIM);
            #pragma unroll
            for (int dt = 0; dt < 4; ++dt) {
                #pragma unroll
                for (int gq = 0; gq < 4; ++gq) {
                    short4v v = { f2bf(o_acc[dt][gq * 4 + 0]), f2bf(o_acc[dt][gq * 4 + 1]),
                                  f2bf(o_acc[dt][gq * 4 + 2]), f2bf(o_acc[dt][gq * 4 + 3]) };
                    *(short4v*)(pp + dt * 32 + 8 * gq + 4 * h5) = v;
                }
            }
            if (h5 == 0) {
                float* mlp = ml + (size_t)part * (2 * NROWSH) + hr * 2;
                mlp[0] = m_run;
                mlp[1] = l_run;
            }
        }
    };

    if constexpr (MODE == 1) {
        const int u = id >> 5;                 // 0..15
        const int k = u & 7;                   // pair index
        const int role = u >> 3;               // 0 = A, 1 = B
        const int jqH = 15 - k, jqL = k;
        const int TH = (16 - k) * 4, TL = (k + 1) * 4;
        const int q0H = jqH * 128 + w * 32;
        if (role == 0) {
            run_segment(q0H, 0, MID, 1, 0);                          // heavy prefix (34)
        } else {
            run_segment(q0H, MID, TH, 1, 1);                         // heavy suffix
            run_segment(jqL * 128 + w * 32, 0, TL, 0, 0);            // light exact; total 34
        }
    } else {
        const int idx = id >> 5;
        const int jq = (idx < 8) ? (15 - idx) : (idx - 8);
        run_segment(jq * 128 + w * 32, 0, (jq + 1) * 4, 0, 0);       // exact path
    }
}

// merge heavy-row 2-way partials
__global__ __launch_bounds__(256)
void qattn_combine2(const unsigned short* __restrict__ po, const float* __restrict__ ml,
                    const float* __restrict__ qsc, const float* __restrict__ ksc,
                    const float* __restrict__ vsc, float* __restrict__ out)
{
    const int gid = blockIdx.x * 256 + threadIdx.x;   // NROWSH*16 threads
    const int hr = gid >> 4;
    const int d0 = (gid & 15) * 8;
    const int h = hr & 15;
    const int q = 1024 + ((hr >> 4) & 1023);
    const int b = hr >> 14;
    const float sc2 = qsc[h] * ksc[h] * (0.08838834764831845f * 1.4426950408889634f);
    const float m0 = ml[(size_t)hr * 2 + 0], l0 = ml[(size_t)hr * 2 + 1];
    const float m1 = ml[(size_t)2 * NROWSH + hr * 2 + 0], l1 = ml[(size_t)2 * NROWSH + hr * 2 + 1];
    const float M = fmaxf(m0, m1);
    const float w0 = exp2f((m0 - M) * sc2);
    const float w1 = exp2f((m1 - M) * sc2);
    const float sr = vsc[h] / __builtin_fmaf(w0, l0, w1 * l1);
    const float a0 = w0 * sr, a1 = w1 * sr;
    const short* x = (const short*)po + (size_t)hr * NDIM + d0;
    const short* y = (const short*)(po + NPARTH) + (size_t)hr * NDIM + d0;
    short4v x0 = *(const short4v*)x;
    short4v x1 = *(const short4v*)(x + 4);
    short4v y0 = *(const short4v*)y;
    short4v y1 = *(const short4v*)(y + 4);
    f32x4 o0, o1;
    #pragma unroll
    for (int i = 0; i < 4; ++i) {
        o0[i] = __builtin_fmaf(a0, bf2f(x0[i]), a1 * bf2f(y0[i]));
        o1[i] = __builtin_fmaf(a0, bf2f(x1[i]), a1 * bf2f(y1[i]));
    }
    float* op = out + ((size_t)(b * NSEQ + q) * NHEAD + h) * NDIM + d0;
    *(f32x4*)op = o0;
    *(f32x4*)(op + 4) = o1;
}

extern "C" void kernel_launch(void* const* d_in, const int* in_sizes, int n_in,
                              void* d_out, int out_size, void* d_ws, size_t ws_size,
                              hipStream_t stream) {
    const int* qq = (const int*)d_in[0];
    const int* kq = (const int*)d_in[1];
    const int* vq = (const int*)d_in[2];
    const float* qsc = (const float*)d_in[3];
    const float* ksc = (const float*)d_in[4];
    const float* vsc = (const float*)d_in[5];
    float* out = (float*)d_out;
    (void)in_sizes; (void)n_in; (void)out_size;

    const size_t need2 = NPARTH * 2 * sizeof(unsigned short)      // two bf16 partial halves
                       + (size_t)NROWSH * 4 * sizeof(float);      // two (m,l) arrays
    if (ws_size >= need2) {
        unsigned short* po = (unsigned short*)d_ws;
        float* ml = (float*)((char*)d_ws + NPARTH * 2 * sizeof(unsigned short));
        qattn_fwd<1><<<dim3(512), dim3(256), 0, stream>>>(qq, kq, vq, qsc, ksc, vsc, out, po, ml);
        qattn_combine2<<<dim3(NROWSH * 16 / 256), dim3(256), 0, stream>>>(po, ml, qsc, ksc, vsc, out);
    } else {
        qattn_fwd<0><<<dim3(512), dim3(256), 0, stream>>>(qq, kq, vq, qsc, ksc, vsc, out, nullptr, nullptr);
    }
}

// Round 22
// 76.744 us; speedup vs baseline: 1.2567x; 1.0253x over previous
//
#include <hip/hip_runtime.h>
#include <hip/hip_bf16.h>

typedef __attribute__((ext_vector_type(8))) short short8;
typedef __attribute__((ext_vector_type(4))) short short4v;
typedef __attribute__((ext_vector_type(4))) float f32x4;
typedef __attribute__((ext_vector_type(16))) float f32x16;
typedef __attribute__((ext_vector_type(4))) int i32x4;
typedef __attribute__((ext_vector_type(16))) int i32x16;
typedef __attribute__((ext_vector_type(2))) unsigned u32x2;

namespace {
constexpr int NSEQ = 2048;
constexpr int NHEAD = 16;
constexpr int NDIM = 128;
constexpr int BKV = 32;
constexpr int VTS = 40;              // vt row stride (shorts); odd*16B -> conflict-free b128 column reads
constexpr int ROWI = NHEAD * NDIM;   // 2048 ints per seq row
constexpr int MID = 34;              // 2-way balanced split point
constexpr int NROWSH = 2 * 1024 * NHEAD;            // heavy rows (q>=1024) = 32768
constexpr size_t NPARTH = (size_t)NROWSH * NDIM;    // elems per heavy partial
}

// int in [-128,127] -> bf16 bits, exact
__device__ __forceinline__ short i2bf(int v) {
    union { float f; unsigned u; } x; x.f = (float)v;
    return (short)(x.u >> 16);
}
// float -> bf16 bits, RNE
__device__ __forceinline__ short f2bf(float f) {
    union { float f; unsigned u; } x; x.f = f;
    unsigned u = (x.u + 0x7fffu + ((x.u >> 16) & 1u)) >> 16;
    return (short)u;
}
__device__ __forceinline__ float bf2f(short s) {
    union { unsigned u; float f; } x; x.u = ((unsigned)(unsigned short)s) << 16;
    return x.f;
}
// 4 int32 (int8 values) -> 1 dword of 4 packed i8
__device__ __forceinline__ unsigned pack8(const int4 &a) {
    return (unsigned)(a.x & 255) | ((unsigned)(a.y & 255) << 8) |
           ((unsigned)(a.z & 255) << 16) | ((unsigned)a.w << 24);
}
// permlane32_swap: a' = [a_lo32 | b_lo32], b' = [a_hi32 | b_hi32]
__device__ __forceinline__ void plswap(unsigned &a, unsigned &b) {
#if __has_builtin(__builtin_amdgcn_permlane32_swap)
    u32x2 r = __builtin_amdgcn_permlane32_swap(a, b, false, false);
    a = r[0]; b = r[1];
#else
    // force b into a distinct register def (round-5 self-swap aliasing hazard)
    unsigned bb;
    asm volatile("v_mov_b32 %0, %1" : "=v"(bb) : "v"(b));
    asm volatile("v_permlane32_swap_b32 %0, %1" : "+v"(a), "+v"(bb));
    b = bb;
#endif
}
// cross-half (lane i <-> i+32) max / sum via permlane32_swap (VALU, not LDS pipe)
__device__ __forceinline__ float xhalf_max(float v) {
    union { float f; unsigned u; } a, b;
    a.f = v; b.f = v;
    plswap(a.u, b.u);
    return fmaxf(a.f, b.f);   // lo lanes: max(own, other-half); hi lanes: max(other-half, own)
}
__device__ __forceinline__ float xhalf_sum(float v) {
    union { float f; unsigned u; } a, b;
    a.f = v; b.f = v;
    plswap(a.u, b.u);
    return a.f + b.f;
}

// MODE: 0 = exact 512-block; 1 = 2-way heavy split (round-10/12 structure)
// NOTE: launch_bounds arg2 MUST stay <=2: arg2=4 empirically caps VGPR at 64 -> catastrophic
// scratch spill (rounds 9/11/13: VGPR_Count 64, WRITE_SIZE 152-466 MB).
// NOTE: no s_setprio: T5/m190 measured setprio as null-to-negative on lockstep barrier schedules.
template<int MODE>
__global__ __launch_bounds__(256, 2)
void qattn_fwd(const int* __restrict__ qq, const int* __restrict__ kq,
               const int* __restrict__ vq, const float* __restrict__ qsc,
               const float* __restrict__ ksc, const float* __restrict__ vsc,
               float* __restrict__ out, unsigned short* __restrict__ po,
               float* __restrict__ ml)
{
    const int id = blockIdx.x;
    const int bh = id & 31;                        // same bh -> same XCD (32%8==0)
    const int b = bh >> 4, h = bh & 15;
    const int t = threadIdx.x;
    const int lane = t & 63;
    const int l31 = lane & 31;
    const int h5 = lane >> 5;
    const int w = t >> 6;                          // wave 0..3

    __shared__ __align__(16) unsigned k_lds[2][BKV * 32];  // 8 KB, packed i8 rows, XOR-swz
    __shared__ __align__(16) short vt_lds[2][NDIM * VTS];  // 20 KB, V^T [d][kv]

    const float sc2 = qsc[h] * ksc[h] * (0.08838834764831845f * 1.4426950408889634f); // /sqrt(D)*log2e
    const float vscale = vsc[h];

    const int* kB = kq + (size_t)b * NSEQ * ROWI + h * NDIM;
    const int* vB = vq + (size_t)b * NSEQ * ROWI + h * NDIM;

    // staging decomposition (256 threads)
    const int kr  = t >> 3;            // K: row 0..31
    const int db  = t & 7;             // K: 16-int group (-> 4 packed dwords)
    const int kvh = t & 7;             // V: kv rows kvh*4..+3
    const int dgv = t >> 3;            // V: d cols dgv*4..+3

    // outMode: 0 = exact -> out; 1 = heavy-layout partial (part 0/1)
    auto run_segment = [&](int q0, int tBeg, int tEnd, int outMode, int part) {
        __syncthreads();               // protect LDS reuse across segments
        // ---- Q fragments (B-operand of 32x32x32_i8): lane owns q col = q0+l31,
        //      chunk c covers d = c*32 + h5*16 + [0,16), packed 4 dwords ----
        i32x4 qf[4];
        {
            const int* qp = qq + (size_t)(b * NSEQ + q0 + l31) * ROWI + h * NDIM + h5 * 16;
            #pragma unroll
            for (int c = 0; c < 4; ++c) {
                int4 a0 = *(const int4*)(qp + c * 32);
                int4 a1 = *(const int4*)(qp + c * 32 + 4);
                int4 a2 = *(const int4*)(qp + c * 32 + 8);
                int4 a3 = *(const int4*)(qp + c * 32 + 12);
                i32x4 f = { (int)pack8(a0), (int)pack8(a1), (int)pack8(a2), (int)pack8(a3) };
                qf[c] = f;
            }
        }
        f32x16 o_acc[4];
        #pragma unroll
        for (int dt = 0; dt < 4; ++dt)
            #pragma unroll
            for (int r = 0; r < 16; ++r) o_acc[dt][r] = 0.f;
        float m_run = -1e30f, l_run = 0.f;
        const int q_hi = q0 + 31;

        int4 ka0, ka1, ka2, ka3, va0, va1, va2, va3;
        auto ISSUE = [&](int tt) {
            const int kv = tt * BKV;
            const int* kp = kB + (kv + kr) * ROWI + db * 16;
            ka0 = *(const int4*)kp;       ka1 = *(const int4*)(kp + 4);
            ka2 = *(const int4*)(kp + 8); ka3 = *(const int4*)(kp + 12);
            const int* vp = vB + (kv + kvh * 4) * ROWI + dgv * 4;
            va0 = *(const int4*)vp;
            va1 = *(const int4*)(vp + ROWI);
            va2 = *(const int4*)(vp + 2 * ROWI);
            va3 = *(const int4*)(vp + 3 * ROWI);
        };
        auto WRITE = [&](int buf) {
            i32x4 kk = { (int)pack8(ka0), (int)pack8(ka1), (int)pack8(ka2), (int)pack8(ka3) };
            *(i32x4*)&k_lds[buf][kr * 32 + ((db * 4) ^ ((kr & 7) << 2))] = kk;   // 16B-group XOR swz
            short4v c0 = { i2bf(va0.x), i2bf(va1.x), i2bf(va2.x), i2bf(va3.x) };
            short4v c1 = { i2bf(va0.y), i2bf(va1.y), i2bf(va2.y), i2bf(va3.y) };
            short4v c2 = { i2bf(va0.z), i2bf(va1.z), i2bf(va2.z), i2bf(va3.z) };
            short4v c3 = { i2bf(va0.w), i2bf(va1.w), i2bf(va2.w), i2bf(va3.w) };
            short* vb = &vt_lds[buf][(dgv * 4) * VTS + kvh * 4];
            *(short4v*)(vb + 0 * VTS) = c0;
            *(short4v*)(vb + 1 * VTS) = c1;
            *(short4v*)(vb + 2 * VTS) = c2;
            *(short4v*)(vb + 3 * VTS) = c3;
        };

        ISSUE(tBeg);
        for (int tt = tBeg; tt < tEnd; ++tt) {
            const int buf = (tt - tBeg) & 1;
            WRITE(buf);
            if (tt + 1 < tEnd) ISSUE(tt + 1);
            __syncthreads();

            const int kv0 = tt * BKV;
            if (kv0 > q_hi) continue;      // wave-uniform causal skip

            // ---- QK^T (swapped, int8 exact): C = S^T, col = l31 = q, kv = (r&3)+8*(r>>2)+4*h5 ----
            i32x16 s;
            #pragma unroll
            for (int r = 0; r < 16; ++r) s[r] = 0;
            #pragma unroll
            for (int c = 0; c < 4; ++c) {
                const i32x4 kb = *(const i32x4*)&k_lds[buf][l31 * 32 + ((c * 8 + h5 * 4) ^ ((l31 & 7) << 2))];
                s = __builtin_amdgcn_mfma_i32_32x32x32_i8(kb, qf[c], s, 0, 0, 0);
            }

            // ---- mask (diag tile only) + int->f32 (exact, |s| < 2^24) ----
            float sv[16];
            if (kv0 < q0) {
                #pragma unroll
                for (int r = 0; r < 16; ++r) sv[r] = (float)s[r];
            } else {                       // kv0 == q0 diag
                #pragma unroll
                for (int r = 0; r < 16; ++r) {
                    const int kvr = (r & 3) + 8 * (r >> 2) + 4 * h5;
                    sv[r] = (kvr <= l31) ? (float)s[r] : -1e30f;
                }
            }

            // ---- in-register softmax (raw-s domain; sc2 > 0 so max commutes) ----
            float rmax = sv[0];
            #pragma unroll
            for (int r = 1; r < 16; ++r) rmax = fmaxf(rmax, sv[r]);
            rmax = xhalf_max(rmax);                            // cross-half max (permlane, VALU)
            const bool needr = (rmax - m_run) * sc2 > 8.0f;    // T13 defer-rescale
            if (__any((int)needr)) {
                const float mn = fmaxf(m_run, rmax);
                const float sf = exp2f((m_run - mn) * sc2);
                m_run = mn;
                l_run *= sf;
                #pragma unroll
                for (int dt = 0; dt < 4; ++dt)
                    #pragma unroll
                    for (int r = 0; r < 16; ++r) o_acc[dt][r] *= sf;
            }
            const float nm = m_run * sc2;
            float p[16];
            float ps = 0.f;
            #pragma unroll
            for (int r = 0; r < 16; ++r) {
                p[r] = exp2f(__builtin_fmaf(sv[r], sc2, -nm));
                ps += p[r];
            }
            l_run += xhalf_sum(ps);                            // cross-half sum (permlane, VALU)

            // ---- P -> bf16 B-frags fully in-register (T12) ----
            unsigned pw0[4], pw1[4];
            {
                unsigned A0, A1, B0, B1;
                asm("v_cvt_pk_bf16_f32 %0, %1, %2" : "=v"(A0) : "v"(p[0]),  "v"(p[1]));
                asm("v_cvt_pk_bf16_f32 %0, %1, %2" : "=v"(A1) : "v"(p[2]),  "v"(p[3]));
                asm("v_cvt_pk_bf16_f32 %0, %1, %2" : "=v"(B0) : "v"(p[4]),  "v"(p[5]));
                asm("v_cvt_pk_bf16_f32 %0, %1, %2" : "=v"(B1) : "v"(p[6]),  "v"(p[7]));
                plswap(A0, B0);
                plswap(A1, B1);
                pw0[0] = A0; pw0[1] = A1; pw0[2] = B0; pw0[3] = B1;
                asm("v_cvt_pk_bf16_f32 %0, %1, %2" : "=v"(A0) : "v"(p[8]),  "v"(p[9]));
                asm("v_cvt_pk_bf16_f32 %0, %1, %2" : "=v"(A1) : "v"(p[10]), "v"(p[11]));
                asm("v_cvt_pk_bf16_f32 %0, %1, %2" : "=v"(B0) : "v"(p[12]), "v"(p[13]));
                asm("v_cvt_pk_bf16_f32 %0, %1, %2" : "=v"(B1) : "v"(p[14]), "v"(p[15]));
                plswap(A0, B0);
                plswap(A1, B1);
                pw1[0] = A0; pw1[1] = A1; pw1[2] = B0; pw1[3] = B1;
            }
            union { unsigned u4[4]; short8 v; } pf0, pf1;
            pf0.u4[0]=pw0[0]; pf0.u4[1]=pw0[1]; pf0.u4[2]=pw0[2]; pf0.u4[3]=pw0[3];
            pf1.u4[0]=pw1[0]; pf1.u4[1]=pw1[1]; pf1.u4[2]=pw1[2]; pf1.u4[3]=pw1[3];

            // ---- PV (swapped): O^T[d][q] += V^T[d][kv] * P^T[kv][q] ----
            #pragma unroll
            for (int dt = 0; dt < 4; ++dt) {
                const int drow = dt * 32 + l31;
                const short8 vb0 = *(const short8*)&vt_lds[buf][drow * VTS + h5 * 8];
                o_acc[dt] = __builtin_amdgcn_mfma_f32_32x32x16_bf16(vb0, pf0.v, o_acc[dt], 0, 0, 0);
                const short8 vb1 = *(const short8*)&vt_lds[buf][drow * VTS + 16 + h5 * 8];
                o_acc[dt] = __builtin_amdgcn_mfma_f32_32x32x16_bf16(vb1, pf1.v, o_acc[dt], 0, 0, 0);
            }
        }

        // ---- epilogue ----
        const int qrow = q0 + l31;
        if (outMode == 0) {
            const float sr = vscale / l_run;
            float* op = out + ((size_t)(b * NSEQ + qrow) * NHEAD + h) * NDIM;
            #pragma unroll
            for (int dt = 0; dt < 4; ++dt) {
                #pragma unroll
                for (int gq = 0; gq < 4; ++gq) {
                    f32x4 v = { o_acc[dt][gq * 4 + 0] * sr, o_acc[dt][gq * 4 + 1] * sr,
                                o_acc[dt][gq * 4 + 2] * sr, o_acc[dt][gq * 4 + 3] * sr };
                    *(f32x4*)(op + dt * 32 + 8 * gq + 4 * h5) = v;
                }
            }
        } else {
            const size_t hr = ((size_t)b * 1024 + (qrow - 1024)) * NHEAD + h;
            short* pp = (short*)(po + (size_t)part * NPARTH + hr * NDIM);
            #pragma unroll
            for (int dt = 0; dt < 4; ++dt) {
                #pragma unroll
                for (int gq = 0; gq < 4; ++gq) {
                    short4v v = { f2bf(o_acc[dt][gq * 4 + 0]), f2bf(o_acc[dt][gq * 4 + 1]),
                                  f2bf(o_acc[dt][gq * 4 + 2]), f2bf(o_acc[dt][gq * 4 + 3]) };
                    *(short4v*)(pp + dt * 32 + 8 * gq + 4 * h5) = v;
                }
            }
            if (h5 == 0) {
                float* mlp = ml + (size_t)part * (2 * NROWSH) + hr * 2;
                mlp[0] = m_run;
                mlp[1] = l_run;
            }
        }
    };

    if constexpr (MODE == 1) {
        const int u = id >> 5;                 // 0..15
        const int k = u & 7;                   // pair index
        const int role = u >> 3;               // 0 = A, 1 = B
        const int jqH = 15 - k, jqL = k;
        const int TH = (16 - k) * 4, TL = (k + 1) * 4;
        const int q0H = jqH * 128 + w * 32;
        if (role == 0) {
            run_segment(q0H, 0, MID, 1, 0);                          // heavy prefix (34)
        } else {
            run_segment(q0H, MID, TH, 1, 1);                         // heavy suffix
            run_segment(jqL * 128 + w * 32, 0, TL, 0, 0);            // light exact; total 34
        }
    } else {
        const int idx = id >> 5;
        const int jq = (idx < 8) ? (15 - idx) : (idx - 8);
        run_segment(jq * 128 + w * 32, 0, (jq + 1) * 4, 0, 0);       // exact path
    }
}

// merge heavy-row 2-way partials
__global__ __launch_bounds__(256)
void qattn_combine2(const unsigned short* __restrict__ po, const float* __restrict__ ml,
                    const float* __restrict__ qsc, const float* __restrict__ ksc,
                    const float* __restrict__ vsc, float* __restrict__ out)
{
    const int gid = blockIdx.x * 256 + threadIdx.x;   // NROWSH*16 threads
    const int hr = gid >> 4;
    const int d0 = (gid & 15) * 8;
    const int h = hr & 15;
    const int q = 1024 + ((hr >> 4) & 1023);
    const int b = hr >> 14;
    const float sc2 = qsc[h] * ksc[h] * (0.08838834764831845f * 1.4426950408889634f);
    const float m0 = ml[(size_t)hr * 2 + 0], l0 = ml[(size_t)hr * 2 + 1];
    const float m1 = ml[(size_t)2 * NROWSH + hr * 2 + 0], l1 = ml[(size_t)2 * NROWSH + hr * 2 + 1];
    const float M = fmaxf(m0, m1);
    const float w0 = exp2f((m0 - M) * sc2);
    const float w1 = exp2f((m1 - M) * sc2);
    const float sr = vsc[h] / __builtin_fmaf(w0, l0, w1 * l1);
    const float a0 = w0 * sr, a1 = w1 * sr;
    const short* x = (const short*)po + (size_t)hr * NDIM + d0;
    const short* y = (const short*)(po + NPARTH) + (size_t)hr * NDIM + d0;
    short4v x0 = *(const short4v*)x;
    short4v x1 = *(const short4v*)(x + 4);
    short4v y0 = *(const short4v*)y;
    short4v y1 = *(const short4v*)(y + 4);
    f32x4 o0, o1;
    #pragma unroll
    for (int i = 0; i < 4; ++i) {
        o0[i] = __builtin_fmaf(a0, bf2f(x0[i]), a1 * bf2f(y0[i]));
        o1[i] = __builtin_fmaf(a0, bf2f(x1[i]), a1 * bf2f(y1[i]));
    }
    float* op = out + ((size_t)(b * NSEQ + q) * NHEAD + h) * NDIM + d0;
    *(f32x4*)op = o0;
    *(f32x4*)(op + 4) = o1;
}

extern "C" void kernel_launch(void* const* d_in, const int* in_sizes, int n_in,
                              void* d_out, int out_size, void* d_ws, size_t ws_size,
                              hipStream_t stream) {
    const int* qq = (const int*)d_in[0];
    const int* kq = (const int*)d_in[1];
    const int* vq = (const int*)d_in[2];
    const float* qsc = (const float*)d_in[3];
    const float* ksc = (const float*)d_in[4];
    const float* vsc = (const float*)d_in[5];
    float* out = (float*)d_out;
    (void)in_sizes; (void)n_in; (void)out_size;

    const size_t need2 = NPARTH * 2 * sizeof(unsigned short)      // two bf16 partial halves
                       + (size_t)NROWSH * 4 * sizeof(float);      // two (m,l) arrays
    if (ws_size >= need2) {
        unsigned short* po = (unsigned short*)d_ws;
        float* ml = (float*)((char*)d_ws + NPARTH * 2 * sizeof(unsigned short));
        qattn_fwd<1><<<dim3(512), dim3(256), 0, stream>>>(qq, kq, vq, qsc, ksc, vsc, out, po, ml);
        qattn_combine2<<<dim3(NROWSH * 16 / 256), dim3(256), 0, stream>>>(po, ml, qsc, ksc, vsc, out);
    } else {
        qattn_fwd<0><<<dim3(512), dim3(256), 0, stream>>>(qq, kq, vq, qsc, ksc, vsc, out, nullptr, nullptr);
    }
}